// Round 7
// baseline (77.904 us; speedup 1.0000x reference)
//
#include <hip/hip_runtime.h>
#include <math.h>

typedef float v2f __attribute__((ext_vector_type(2)));
typedef float v4f __attribute__((ext_vector_type(4)));

#define TPB 256
#define KX 8        // query points per thread
#define PEPASS 128  // pair-entries staged in LDS per pass (4 KB)

// For each query point a in A: min over a chunk of B of t = c - 2 a.b
// (c=|b|^2); then atomicMin(gmin[a], bits(a^2 + min t)) -- nonneg fp32 bit
// patterns are monotone as uint, so uint atomicMin == float min, exactly.
// B staged in LDS as {-2x0,-2x1,-2y0,-2y1},{-2z0,-2z1,c0,c1} pair-entries.
// dir (blockIdx.z): 0 = forward (A=P, B=T), 1 = backward (A=T, B=P).
//
// Register-cap history: (256,8) caps VGPR at 64 -> compiler squeezed KX-state
// and spilled (r4: WRITE 112MB; r6: VGPR=32, WRITE 16MB scratch). (256,6)
// caps at ~84 which fits the ~60-76 live set (r3 measured 60 for KX=8).
// KX=8 also halves LDS broadcast traffic per FLOP vs KX=4 -- at KX=4 the
// per-CU LDS return bus (2 b128/jj/wave) exceeds the VALU pipe and the
// barrier phase-aligns the bursts (r5/r6: wall pinned at ~50us, VALUBusy 61%).
__global__ __launch_bounds__(TPB, 6) void chamfer_minsq(
    const float* __restrict__ P, int NP,
    const float* __restrict__ T, int NT,
    unsigned* __restrict__ gminF, unsigned* __restrict__ gminB, int YC)
{
    const int dir = blockIdx.z;
    const float* __restrict__ A = dir ? T : P;
    const float* __restrict__ B = dir ? P : T;
    const int NA = dir ? NT : NP;
    const int NB = dir ? NP : NT;
    unsigned* __restrict__ gmin = dir ? gminB : gminF;

    const int tid = threadIdx.x;
    const int xbase = blockIdx.x * (TPB * KX);
    if (xbase >= NA) return;

    const int NBp = (NB + 1) >> 1;               // pair-entry count
    const int chunkp = (NBp + YC - 1) / YC;
    const int p0 = blockIdx.y * chunkp;
    const int p1 = min(p0 + chunkp, NBp);
    if (p0 >= p1) return;                         // chunk 0 always covers all queries

    v2f axp[KX], ayp[KX], azp[KX];
    float m[KX], a2[KX];
#pragma unroll
    for (int k = 0; k < KX; k++) {
        const int xi = xbase + k * TPB + tid;
        const int xc = xi < NA ? xi : NA - 1;     // duplicate query, harmless
        const float ax = A[3*xc], ay = A[3*xc+1], az = A[3*xc+2];
        axp[k] = (v2f){ax, ax};
        ayp[k] = (v2f){ay, ay};
        azp[k] = (v2f){az, az};
        a2[k] = ax*ax + ay*ay + az*az;
        m[k] = 3.4e38f;
    }

    __shared__ v4f lds[2 * PEPASS];               // 4 KB

    for (int base = p0; base < p1; base += PEPASS) {
        const int npe = min(PEPASS, p1 - base);

        // cooperative stage: raw B -> transformed pair-entries in LDS
        for (int t = tid; t < npe; t += TPB) {
            const int j = base + t;
            const int i0 = 2 * j;
            const int i1 = min(2 * j + 1, NB - 1);    // odd NB: duplicate last
            const float x0 = B[3*i0], y0 = B[3*i0+1], z0 = B[3*i0+2];
            const float x1 = B[3*i1], y1 = B[3*i1+1], z1 = B[3*i1+2];
            lds[2*t]   = (v4f){-2.f*x0, -2.f*x1, -2.f*y0, -2.f*y1};
            lds[2*t+1] = (v4f){-2.f*z0, -2.f*z1,
                               x0*x0 + y0*y0 + z0*z0,
                               x1*x1 + y1*y1 + z1*z1};
        }
        __syncthreads();

        // De-phased sweep: wave w starts at npe*w/4 and wraps. Min is
        // order-independent; this stops the block's 4 waves from hitting the
        // same LDS line on the same cycle after the barrier.
        const int start = (npe * (tid >> 6)) >> 2;
        for (int seg = 0; seg < 2; ++seg) {
            const int lo = seg ? 0 : start;
            const int hi = seg ? start : npe;
#pragma unroll 4
            for (int jj = lo; jj < hi; ++jj) {
                const v4f q0 = lds[2*jj];             // ds_read_b128 broadcast
                const v4f q1 = lds[2*jj + 1];
                const v2f mx = (v2f){q0.x, q0.y};
                const v2f my = (v2f){q0.z, q0.w};
                const v2f mz = (v2f){q1.x, q1.y};
                const v2f cv = (v2f){q1.z, q1.w};
#pragma unroll
                for (int k = 0; k < KX; k++) {
                    v2f t = azp[k] * mz + cv;         // fp-contract -> fma
                    t = ayp[k] * my + t;
                    t = axp[k] * mx + t;
                    m[k] = fminf(m[k], fminf(t.x, t.y));  // -> v_min3_f32
                }
            }
        }
        __syncthreads();
    }

#pragma unroll
    for (int k = 0; k < KX; k++) {
        const int xi = xbase + k * TPB + tid;
        if (xi < NA)
            atomicMin(&gmin[xi], __float_as_uint(a2[k] + m[k]));
    }
}

// gmin bits -> sqrt -> scaled sum into *out.
__global__ __launch_bounds__(TPB) void chamfer_final(
    const unsigned* __restrict__ gminF, int NP,
    const unsigned* __restrict__ gminB, int NT,
    float scaleF, float scaleB, float* __restrict__ out)
{
    const int gid = blockIdx.x * TPB + threadIdx.x;
    float val = 0.f;
    if (gid < NP) {
        val = sqrtf(fmaxf(__uint_as_float(gminF[gid]), 0.f)) * scaleF;
    } else if (gid < NP + NT) {
        val = sqrtf(fmaxf(__uint_as_float(gminB[gid - NP]), 0.f)) * scaleB;
    }

#pragma unroll
    for (int off = 32; off > 0; off >>= 1) val += __shfl_down(val, off);
    __shared__ float red[TPB / 64];
    const int lane = threadIdx.x & 63;
    const int w = threadIdx.x >> 6;
    if (lane == 0) red[w] = val;
    __syncthreads();
    if (threadIdx.x == 0) {
        float s = 0.f;
#pragma unroll
        for (int i = 0; i < TPB / 64; i++) s += red[i];
        atomicAdd(out, s);
    }
}

extern "C" void kernel_launch(void* const* d_in, const int* in_sizes, int n_in,
                              void* d_out, int out_size, void* d_ws, size_t ws_size,
                              hipStream_t stream) {
    const float* P = (const float*)d_in[0];
    const float* T = (const float*)d_in[1];
    const int NP = in_sizes[0] / 3;
    const int NT = in_sizes[1] / 3;
    float* out = (float*)d_out;

    unsigned* gminF = (unsigned*)d_ws;
    unsigned* gminB = gminF + NP;

    // init gmin to 0xFFFFFFFF (uint max) and out to 0, every call (harness
    // poisons once and never re-poisons; no state may persist across calls)
    hipMemsetAsync(d_ws, 0xFF, (size_t)(NP + NT) * sizeof(unsigned), stream);
    hipMemsetAsync(d_out, 0, sizeof(float), stream);

    const int YC = 128;  // y-chunks: grid = gx*YC*2 = 2048 blocks (8/CU)
    const int NAmax = NP > NT ? NP : NT;
    const int gx = (NAmax + TPB * KX - 1) / (TPB * KX);
    dim3 grid(gx, YC, 2);
    chamfer_minsq<<<grid, TPB, 0, stream>>>(P, NP, T, NT, gminF, gminB, YC);

    const int fblocks = (NP + NT + TPB - 1) / TPB;
    chamfer_final<<<fblocks, TPB, 0, stream>>>(gminF, NP, gminB, NT,
                                               1.0f / (float)NP, 1.0f / (float)NT, out);
}

// Round 8
// 54.054 us; speedup vs baseline: 1.4412x; 1.4412x over previous
//
#include <hip/hip_runtime.h>
#include <math.h>

typedef _Float16 f16;
typedef _Float16 f16x8 __attribute__((ext_vector_type(8)));
typedef float f32x16 __attribute__((ext_vector_type(16)));

#define TPB 256
#define RB 2                        // 32-row MFMA blocks per wave
#define ROWS_PER_BLOCK (4*RB*32)    // 256 rows per block (4 waves)
#define CC 1024                     // B-points per chunk (32 KB LDS)

static __device__ __forceinline__ unsigned pk(f16 a, f16 b) {
    union { f16 h[2]; unsigned u; } v; v.h[0] = a; v.h[1] = b; return v.u;
}

// Encode each point p as two 16-slot f16 K-vectors such that
//   enc_row(a) . enc_col(b) = |a|^2 + |b|^2 - 2 a.b  (= d^2)  to ~4e-5.
// hi/lo split per Markidis: u=-2x -> uh,ul; x' -> xh,xl; slots pair
// (uh,xh),(ul,xh),(uh,xl) so only ul*xl (~1e-5) is dropped. |a|^2 terms
// are hi/lo split against 1-slots. 13 slots used, 3 zero (K=16 of MFMA).
__global__ __launch_bounds__(TPB) void chamfer_encode(
    const float* __restrict__ P, int NP, const float* __restrict__ T, int NT,
    ushort* __restrict__ Prow, ushort* __restrict__ Pcol,
    ushort* __restrict__ Trow, ushort* __restrict__ Tcol)
{
    const int i = blockIdx.x * TPB + threadIdx.x;
    if (i >= NP + NT) return;
    const float* S; ushort *R, *C; int j;
    if (i < NP) { S = P; R = Prow; C = Pcol; j = i; }
    else        { S = T; R = Trow; C = Tcol; j = i - NP; }

    const float x = S[3*j], y = S[3*j+1], z = S[3*j+2];
    const float s2 = x*x + y*y + z*z;
    const float ux = -2.f*x, uy = -2.f*y, uz = -2.f*z;

    const f16 xh = (f16)x,  xl = (f16)(x - (float)xh);
    const f16 yh = (f16)y,  yl = (f16)(y - (float)yh);
    const f16 zh = (f16)z,  zl = (f16)(z - (float)zh);
    const f16 uxh = (f16)ux, uxl = (f16)(ux - (float)uxh);
    const f16 uyh = (f16)uy, uyl = (f16)(uy - (float)uyh);
    const f16 uzh = (f16)uz, uzl = (f16)(uz - (float)uzh);
    const f16 sh = (f16)s2, sl = (f16)(s2 - (float)sh);
    const f16 one = (f16)1.f, zer = (f16)0.f;

    // row (query) enc: [uxh,uxl,uxh, uyh,uyl,uyh, uzh,uzl,uzh, sh,sl, 1,1, 0,0,0]
    uint4 r0 = { pk(uxh,uxl), pk(uxh,uyh), pk(uyl,uyh), pk(uzh,uzl) };
    uint4 r1 = { pk(uzh,sh),  pk(sl,one),  pk(one,zer), pk(zer,zer) };
    // col (target) enc: [xh,xh,xl, yh,yh,yl, zh,zh,zl, 1,1, sh,sl, 0,0,0]
    uint4 c0 = { pk(xh,xh), pk(xl,yh), pk(yh,yl), pk(zh,zh) };
    uint4 c1 = { pk(zl,one), pk(one,sh), pk(sl,zer), pk(zer,zer) };

    *(uint4*)(R + (size_t)j*16)     = r0;
    *(uint4*)(R + (size_t)j*16 + 8) = r1;
    *(uint4*)(C + (size_t)j*16)     = c0;
    *(uint4*)(C + (size_t)j*16 + 8) = c1;
}

// D = A.B via v_mfma_f32_32x32x16_f16 gives a 32x32 tile of d^2 directly.
// Running row-min stays in the C-register layout (m74/m101-verified:
// col=lane&31, row=(reg&3)+8*(reg>>2)+4*(lane>>5)); shfl-reduce over the
// 32 cols once per block, then atomicMin(uint bits) into gmin.
// pass (blockIdx.z): 0 = rows P / cols T (forward), 1 = rows T / cols P.
__global__ __launch_bounds__(TPB) void chamfer_mfma(
    const ushort* __restrict__ Prow, int NP, const ushort* __restrict__ Pcol,
    const ushort* __restrict__ Trow, int NT, const ushort* __restrict__ Tcol,
    unsigned* __restrict__ gminF, unsigned* __restrict__ gminB)
{
    const int pass = blockIdx.z;
    const ushort* __restrict__ Aenc = pass ? Trow : Prow;
    const ushort* __restrict__ Benc = pass ? Pcol : Tcol;
    const int NA = pass ? NT : NP;
    const int NB = pass ? NP : NT;
    unsigned* __restrict__ gmin = pass ? gminB : gminF;

    const int rowbase = blockIdx.x * ROWS_PER_BLOCK;
    const int col0 = blockIdx.y * CC;
    if (rowbase >= NA || col0 >= NB) return;

    __shared__ ushort Alds[ROWS_PER_BLOCK * 16];  // 8 KB
    __shared__ ushort Blds[CC * 16];              // 32 KB

    const int tid = threadIdx.x;
    {   // stage A: one encoded row (32 B) per thread
        const int r = min(rowbase + tid, NA - 1);
        const uint4* s = (const uint4*)(Aenc + (size_t)r * 16);
        uint4* d = (uint4*)(Alds + tid * 16);
        d[0] = s[0]; d[1] = s[1];
    }
    for (int t = tid; t < CC; t += TPB) {   // stage B chunk
        const int c = min(col0 + t, NB - 1);      // clamp: duplicate cols can't affect min
        const uint4* s = (const uint4*)(Benc + (size_t)c * 16);
        uint4* d = (uint4*)(Blds + t * 16);
        d[0] = s[0]; d[1] = s[1];
    }
    __syncthreads();

    const int l = tid & 63, w = tid >> 6;
    const int kg = l >> 5;     // k-group: lane's 8 f16 cover k = kg*8..kg*8+7
    const int ln = l & 31;     // row (A) / col (B) within the 32-tile

    f16x8 af[RB];
#pragma unroll
    for (int rb = 0; rb < RB; rb++) {
        const int row = (w * RB + rb) * 32 + ln;
        af[rb] = *(const f16x8*)(Alds + row * 16 + kg * 8);
    }

    f32x16 mr[RB];
#pragma unroll
    for (int rb = 0; rb < RB; rb++)
#pragma unroll
        for (int r = 0; r < 16; r++) mr[rb][r] = 3.4e38f;

#pragma unroll 2
    for (int cb = 0; cb < CC / 32; cb++) {
        const f16x8 bf = *(const f16x8*)(Blds + (cb * 32 + ln) * 16 + kg * 8);
#pragma unroll
        for (int rb = 0; rb < RB; rb++) {
            f32x16 zacc = {0,0,0,0,0,0,0,0,0,0,0,0,0,0,0,0};
            f32x16 d = __builtin_amdgcn_mfma_f32_32x32x16_f16(af[rb], bf, zacc, 0, 0, 0);
#pragma unroll
            for (int r = 0; r < 16; r++) mr[rb][r] = fminf(mr[rb][r], d[r]);
        }
    }

    // reduce over the 32 cols (lane bits 0-4), then one atomicMin per row
#pragma unroll
    for (int rb = 0; rb < RB; rb++) {
#pragma unroll
        for (int r = 0; r < 16; r++) {
            float v = mr[rb][r];
            v = fminf(v, __shfl_xor(v, 1));
            v = fminf(v, __shfl_xor(v, 2));
            v = fminf(v, __shfl_xor(v, 4));
            v = fminf(v, __shfl_xor(v, 8));
            v = fminf(v, __shfl_xor(v, 16));
            if (ln == 0) {
                const int row = rowbase + (w * RB + rb) * 32 + (r & 3) + 8 * (r >> 2) + 4 * kg;
                if (row < NA)
                    atomicMin(&gmin[row], __float_as_uint(fmaxf(v, 0.f)));
            }
        }
    }
}

// gmin bits -> sqrt -> scaled sum into *out.
__global__ __launch_bounds__(TPB) void chamfer_final(
    const unsigned* __restrict__ gminF, int NP,
    const unsigned* __restrict__ gminB, int NT,
    float scaleF, float scaleB, float* __restrict__ out)
{
    const int gid = blockIdx.x * TPB + threadIdx.x;
    float val = 0.f;
    if (gid < NP) {
        val = sqrtf(fmaxf(__uint_as_float(gminF[gid]), 0.f)) * scaleF;
    } else if (gid < NP + NT) {
        val = sqrtf(fmaxf(__uint_as_float(gminB[gid - NP]), 0.f)) * scaleB;
    }
#pragma unroll
    for (int off = 32; off > 0; off >>= 1) val += __shfl_down(val, off);
    __shared__ float red[TPB / 64];
    const int lane = threadIdx.x & 63;
    const int w = threadIdx.x >> 6;
    if (lane == 0) red[w] = val;
    __syncthreads();
    if (threadIdx.x == 0) {
        float s = 0.f;
#pragma unroll
        for (int i = 0; i < TPB / 64; i++) s += red[i];
        atomicAdd(out, s);
    }
}

extern "C" void kernel_launch(void* const* d_in, const int* in_sizes, int n_in,
                              void* d_out, int out_size, void* d_ws, size_t ws_size,
                              hipStream_t stream) {
    const float* P = (const float*)d_in[0];
    const float* T = (const float*)d_in[1];
    const int NP = in_sizes[0] / 3;
    const int NT = in_sizes[1] / 3;
    float* out = (float*)d_out;

    unsigned* gminF = (unsigned*)d_ws;
    unsigned* gminB = gminF + NP;
    ushort* Prow = (ushort*)(gminB + NT);
    ushort* Pcol = Prow + (size_t)NP * 16;
    ushort* Trow = Pcol + (size_t)NP * 16;
    ushort* Tcol = Trow + (size_t)NT * 16;
    // ws usage: (NP+NT)*4 + (NP+NT)*64 bytes = ~2.3 MB << ws (>=16.8 MB per r4/r5)

    hipMemsetAsync(d_ws, 0xFF, (size_t)(NP + NT) * sizeof(unsigned), stream);
    hipMemsetAsync(d_out, 0, sizeof(float), stream);

    const int eblocks = (NP + NT + TPB - 1) / TPB;
    chamfer_encode<<<eblocks, TPB, 0, stream>>>(P, NP, T, NT, Prow, Pcol, Trow, Tcol);

    const int NAmax = NP > NT ? NP : NT;
    dim3 grid((NAmax + ROWS_PER_BLOCK - 1) / ROWS_PER_BLOCK,
              (NAmax + CC - 1) / CC, 2);
    chamfer_mfma<<<grid, TPB, 0, stream>>>(Prow, NP, Pcol, Trow, NT, Tcol, gminF, gminB);

    const int fblocks = (NP + NT + TPB - 1) / TPB;
    chamfer_final<<<fblocks, TPB, 0, stream>>>(gminF, NP, gminB, NT,
                                               1.0f / (float)NP, 1.0f / (float)NT, out);
}